// Round 18
// baseline (117.712 us; speedup 1.0000x reference)
//
#include <hip/hip_runtime.h>
#include <hip/hip_bf16.h>
#include <math.h>

#define BB 2
#define TT 1024
#define CC 2048
#define NH 16
#define NKV 4
#define HD 128
#define MROWS 2048
#define QKVN 3072              // 2048 q + 512 k + 512 v
#define KOFF 2048
#define VOFF 2560

typedef unsigned short u16;
typedef unsigned int   u32;
typedef _Float16 f16;
typedef _Float16 f16x8 __attribute__((ext_vector_type(8)));
typedef short    s16x8 __attribute__((ext_vector_type(8)));
typedef float    f32x4 __attribute__((ext_vector_type(4)));

__device__ __forceinline__ u16 f2h(float f) {
    union { f16 h; u16 u; } x; x.h = (f16)f; return x.u;
}
__device__ __forceinline__ float h2f(u16 u) {
    union { u16 u; f16 h; } x; x.u = u; return (float)x.h;
}

#define GLDS(gp, lp) __builtin_amdgcn_global_load_lds( \
    (const __attribute__((address_space(1))) u32*)(gp), \
    (__attribute__((address_space(3))) u32*)(lp), 16, 0, 0)

// ---------------------------------------------------------------------------
// wT_tile: one 32x32 transpose-convert tile
// ---------------------------------------------------------------------------
__device__ __forceinline__ void wT_tile(const float* __restrict__ src,
                                        u16* __restrict__ Wt, int Nsrc,
                                        int row_off, int idx, int t,
                                        float tile[32][33]) {
    const int k0 = (idx & 63) * 32;
    const int n0 = (idx >> 6) * 32;
    const int r = t >> 3, c4 = (t & 7) * 4;
    float4 v = *(const float4*)&src[(size_t)(k0 + r) * Nsrc + n0 + c4];
    tile[r][c4 + 0] = v.x; tile[r][c4 + 1] = v.y;
    tile[r][c4 + 2] = v.z; tile[r][c4 + 3] = v.w;
    __syncthreads();
    ushort4 o;
    o.x = f2h(tile[c4 + 0][r]); o.y = f2h(tile[c4 + 1][r]);
    o.z = f2h(tile[c4 + 2][r]); o.w = f2h(tile[c4 + 3][r]);
    *(ushort4*)&Wt[(size_t)(row_off + n0 + r) * 2048 + k0 + c4] = o;
}

// ---------------------------------------------------------------------------
// prep: one launch for all conversions (x->f16, 4x W^T, sincos table).
// ---------------------------------------------------------------------------
__global__ __launch_bounds__(256) void prep(const float* __restrict__ x,
                                            const float* __restrict__ wq,
                                            const float* __restrict__ wk,
                                            const float* __restrict__ wv,
                                            const float* __restrict__ wo,
                                            const float* __restrict__ angles,
                                            u16* __restrict__ xb,
                                            u16* __restrict__ Wt1,
                                            u16* __restrict__ Wt2,
                                            float2* __restrict__ cs) {
    __shared__ float tile[32][33];
    const int bid = blockIdx.x, t = threadIdx.x;
    if (bid < 4096) {                 // x -> fp16, 4 elems/thread
        int i = bid * 256 + t;
        float4 v = ((const float4*)x)[i];
        ushort4 o;
        o.x = f2h(v.x); o.y = f2h(v.y); o.z = f2h(v.z); o.w = f2h(v.w);
        ((ushort4*)xb)[i] = o;
    } else if (bid < 8192) {
        wT_tile(wq, Wt1, 2048, 0,    bid - 4096, t, tile);
    } else if (bid < 9216) {
        wT_tile(wk, Wt1, 512,  2048, bid - 8192, t, tile);
    } else if (bid < 10240) {
        wT_tile(wv, Wt1, 512,  2560, bid - 9216, t, tile);
    } else if (bid < 14336) {
        wT_tile(wo, Wt2, 2048, 0,    bid - 10240, t, tile);
    } else {
        int i = (bid - 14336) * 256 + t;   // < 65536
        float a = angles[i];
        cs[i] = make_float2(cosf(a), sinf(a));
    }
}

// ---------------------------------------------------------------------------
// gemm_qkv (round-17, unchanged): 128x96 tiles, 512 blocks (XCD-swizzled),
// 4 waves, 16x16x32 MFMAs, BK=64 dbuf.  Fused RoPE + V^T epilogue.
// ---------------------------------------------------------------------------
__global__ __launch_bounds__(256) void gemm_qkv(const u16* __restrict__ A,
                                                const u16* __restrict__ Bt,
                                                u16* __restrict__ qkv,
                                                u16* __restrict__ vtg,
                                                const float2* __restrict__ cs) {
    __shared__ __align__(16) u16 As0[128 * 64];
    __shared__ __align__(16) u16 As1[128 * 64];
    __shared__ __align__(16) u16 Bs0[96 * 64];
    __shared__ __align__(16) u16 Bs1[96 * 64];
    const int t = threadIdx.x, l = t & 63, w = t >> 6;
    const int bid = blockIdx.x;                 // 512
    const int xcd = bid & 7, idx = bid >> 3;    // 64 blocks per XCD
    const int bx = xcd * 4 + (idx & 3);         // col-tile 0..31
    const int by = idx >> 2;                    // row-tile 0..15
    const int row0 = by * 128;
    const int col0 = bx * 96;
    const int wr = w >> 1, wc = w & 1;
    const int lg = l >> 4, ll = l & 15;
    const int K = 2048;

    f32x4 acc[4][3] = {};

#define QSTAGE(AS, BS, k0v) do {                                              \
    _Pragma("unroll")                                                         \
    for (int e_ = 0; e_ < 4; ++e_) {                                          \
        int r_ = 32 * w + 8 * e_ + (l >> 3);                                  \
        int cg_ = (l & 7) ^ (r_ & 7);                                         \
        GLDS(A + (size_t)(row0 + r_) * K + (k0v) + cg_ * 8,                   \
             (AS) + (32 * w + 8 * e_) * 64);                                  \
    }                                                                         \
    _Pragma("unroll")                                                         \
    for (int e_ = 0; e_ < 3; ++e_) {                                          \
        int r_ = 24 * w + 8 * e_ + (l >> 3);                                  \
        int cg_ = (l & 7) ^ (r_ & 7);                                         \
        GLDS(Bt + (size_t)(col0 + r_) * K + (k0v) + cg_ * 8,                  \
             (BS) + (24 * w + 8 * e_) * 64);                                  \
    }                                                                         \
} while (0)

#define QCOMP(AS, BS) do {                                                    \
    _Pragma("unroll")                                                         \
    for (int kc_ = 0; kc_ < 2; ++kc_) {                                       \
        f16x8 af_[4], bf_[3];                                                 \
        _Pragma("unroll")                                                     \
        for (int m_ = 0; m_ < 4; ++m_) {                                      \
            int row_ = wr * 64 + 16 * m_ + ll;                                \
            af_[m_] = *(const f16x8*)&(AS)[row_ * 64 +                        \
                        (((lg + 4 * kc_) ^ (ll & 7)) * 8)];                   \
        }                                                                     \
        _Pragma("unroll")                                                     \
        for (int n_ = 0; n_ < 3; ++n_) {                                      \
            int col_ = wc * 48 + 16 * n_ + ll;                                \
            bf_[n_] = *(const f16x8*)&(BS)[col_ * 64 +                        \
                        (((lg + 4 * kc_) ^ (ll & 7)) * 8)];                   \
        }                                                                     \
        _Pragma("unroll")                                                     \
        for (int m_ = 0; m_ < 4; ++m_)                                        \
            _Pragma("unroll")                                                 \
            for (int n_ = 0; n_ < 3; ++n_)                                    \
                acc[m_][n_] = __builtin_amdgcn_mfma_f32_16x16x32_f16(         \
                    af_[m_], bf_[n_], acc[m_][n_], 0, 0, 0);                  \
    }                                                                         \
} while (0)

    QSTAGE(As0, Bs0, 0);
    __syncthreads();
#pragma unroll 1
    for (int i = 0; i < 32; i += 2) {
        QSTAGE(As1, Bs1, (i + 1) * 64);
        QCOMP(As0, Bs0);
        __syncthreads();
        if (i + 2 < 32) QSTAGE(As0, Bs0, (i + 2) * 64);
        QCOMP(As1, Bs1);
        __syncthreads();
    }
#undef QSTAGE
#undef QCOMP

    // fused epilogue
    const int orow = row0 + wr * 64 + lg * 4;
    const int ocol = col0 + wc * 48 + ll;
#pragma unroll
    for (int n = 0; n < 3; ++n) {
        const int col = ocol + 16 * n;
        if (col < VOFF) {
            const int p = (col & 127) >> 1;
            const bool odd = ll & 1;
#pragma unroll
            for (int m = 0; m < 4; ++m) {
#pragma unroll
                for (int r = 0; r < 4; ++r) {
                    float v = acc[m][n][r];
                    float pr = __shfl_xor(v, 1);
                    int row = orow + 16 * m + r;
                    float2 a = cs[(row & (TT - 1)) * 64 + p];
                    float res = odd ? (a.y * pr + a.x * v) : (a.x * v - a.y * pr);
                    qkv[(size_t)row * QKVN + col] = f2h(res);
                }
            }
        } else {
            int d = col - VOFF;
            const int hk = d >> 7; d &= 127;
            const int bb = orow >> 10;
            const int base_j = orow & (TT - 1);
#pragma unroll
            for (int m = 0; m < 4; ++m) {
                ushort4 pk;
                pk.x = f2h(acc[m][n][0]); pk.y = f2h(acc[m][n][1]);
                pk.z = f2h(acc[m][n][2]); pk.w = f2h(acc[m][n][3]);
                *(ushort4*)&vtg[((size_t)(bb * NKV + hk) * 128 + d) * 1024 + base_j + 16 * m] = pk;
            }
        }
    }
}

// ---------------------------------------------------------------------------
// gemm_out v5 (round-17, unchanged): 128x64 tiles, 512 blocks = 2 blocks/CU,
// 4 waves, 16x16x32 MFMAs, BK=64 dbuf, fp32 direct out, XCD-swizzled.
// ---------------------------------------------------------------------------
__global__ __launch_bounds__(256) void gemm_out(const u16* __restrict__ A,
                                                const u16* __restrict__ Bt,
                                                float* __restrict__ Cf) {
    __shared__ __align__(16) u16 As0[128 * 64];
    __shared__ __align__(16) u16 As1[128 * 64];
    __shared__ __align__(16) u16 Bs0[64 * 64];
    __shared__ __align__(16) u16 Bs1[64 * 64];
    const int t = threadIdx.x, l = t & 63, w = t >> 6;
    const int bid = blockIdx.x;                 // 512
    const int xcd = bid & 7, idx = bid >> 3;    // 64 blocks per XCD
    const int bx = xcd * 4 + (idx & 3);         // col-tile 0..31
    const int by = idx >> 2;                    // row-tile 0..15
    const int row0 = by * 128;
    const int col0 = bx * 64;
    const int wr = w >> 1, wc = w & 1;
    const int lg = l >> 4, ll = l & 15;
    const int K = 2048;

    f32x4 acc[4][2] = {};

#define GSTAGE(AS, BS, k0v) do {                                              \
    _Pragma("unroll")                                                         \
    for (int e_ = 0; e_ < 4; ++e_) {                                          \
        int r_ = 32 * w + 8 * e_ + (l >> 3);                                  \
        int cg_ = (l & 7) ^ (r_ & 7);                                         \
        GLDS(A + (size_t)(row0 + r_) * K + (k0v) + cg_ * 8,                   \
             (AS) + (32 * w + 8 * e_) * 64);                                  \
    }                                                                         \
    _Pragma("unroll")                                                         \
    for (int e_ = 0; e_ < 2; ++e_) {                                          \
        int r_ = 16 * w + 8 * e_ + (l >> 3);                                  \
        int cg_ = (l & 7) ^ (r_ & 7);                                         \
        GLDS(Bt + (size_t)(col0 + r_) * K + (k0v) + cg_ * 8,                  \
             (BS) + (16 * w + 8 * e_) * 64);                                  \
    }                                                                         \
} while (0)

#define GCOMP(AS, BS) do {                                                    \
    _Pragma("unroll")                                                         \
    for (int kc_ = 0; kc_ < 2; ++kc_) {                                       \
        f16x8 af_[4], bf_[2];                                                 \
        _Pragma("unroll")                                                     \
        for (int m_ = 0; m_ < 4; ++m_) {                                      \
            int row_ = wr * 64 + 16 * m_ + ll;                                \
            af_[m_] = *(const f16x8*)&(AS)[row_ * 64 +                        \
                        (((lg + 4 * kc_) ^ (ll & 7)) * 8)];                   \
        }                                                                     \
        _Pragma("unroll")                                                     \
        for (int n_ = 0; n_ < 2; ++n_) {                                      \
            int col_ = wc * 32 + 16 * n_ + ll;                                \
            bf_[n_] = *(const f16x8*)&(BS)[col_ * 64 +                        \
                        (((lg + 4 * kc_) ^ (ll & 7)) * 8)];                   \
        }                                                                     \
        _Pragma("unroll")                                                     \
        for (int m_ = 0; m_ < 4; ++m_)                                        \
            _Pragma("unroll")                                                 \
            for (int n_ = 0; n_ < 2; ++n_)                                    \
                acc[m_][n_] = __builtin_amdgcn_mfma_f32_16x16x32_f16(         \
                    af_[m_], bf_[n_], acc[m_][n_], 0, 0, 0);                  \
    }                                                                         \
} while (0)

    GSTAGE(As0, Bs0, 0);
    __syncthreads();
#pragma unroll 1
    for (int i = 0; i < 32; i += 2) {
        GSTAGE(As1, Bs1, (i + 1) * 64);
        GCOMP(As0, Bs0);
        __syncthreads();
        if (i + 2 < 32) GSTAGE(As0, Bs0, (i + 2) * 64);
        GCOMP(As1, Bs1);
        __syncthreads();
    }
#undef GSTAGE
#undef GCOMP

    const int orow = row0 + wr * 64 + lg * 4;
    const int ocol = col0 + wc * 32 + ll;
#pragma unroll
    for (int m = 0; m < 4; ++m)
#pragma unroll
        for (int nn = 0; nn < 2; ++nn)
#pragma unroll
            for (int r = 0; r < 4; ++r)
                Cf[(size_t)(orow + 16 * m + r) * CC + ocol + 16 * nn] =
                    acc[m][nn][r];
}

// ---------------------------------------------------------------------------
// MFMA flash attention v5: j-split flash-decoding inside each block.
// Block handles i-tile pair {x, 15-x} (two sequential phases).  Per phase,
// the two 4-wave groups split the j-range: group A = tiles [0,h), group B =
// [h,nt), h = ceil(nt/2); each group has its own Q/Vt double-buffer and an
// independent online softmax; exact flash merge at phase end.  Critical path
// ceil((16-x)/2) + ceil((x+1)/2) = 9 rounds for all x (was 16).
// LDS 146 KB -> 1 block/CU, 8 waves.
// ---------------------------------------------------------------------------
__global__ __launch_bounds__(512, 1) void attn_mfma(const u16* __restrict__ qkv,
                                                    const u16* __restrict__ vtg,
                                                    u16* __restrict__ attnb) {
    // carve: QT[grp][buf] 64x128, VT[grp][buf] 128x64, Ps 8x16x72 (u16 units)
    __shared__ __align__(16) u16 SM[74752];
    const int t = threadIdx.x, l = t & 63, w = t >> 6;   // w in 0..7
    const int grp = w >> 2, wg = w & 3;
    const int bh = blockIdx.y;
    const int b = bh >> 4, h = bh & 15, hk = h & 3;
    const int lg = l >> 4, ll = l & 15;
    const int x = blockIdx.x;             // 0..7

    u16* QT[2];  u16* VT[2];
    QT[0] = SM + grp * 16384;             // [buf0, buf1] contiguous 8192 each
    QT[1] = QT[0] + 8192;
    VT[0] = SM + 32768 + grp * 16384;
    VT[1] = VT[0] + 8192;
    u16* Ps = SM + 65536;
    float* sc = (float*)SM;               // merge scratch (40 KB, post-loop)

    const u16* qbase = qkv + (size_t)(b * TT) * QKVN + h * 128;
    const u16* vbase = vtg + (size_t)((b * NKV + hk) * 128) * 1024;

// group stages one full 64x128 Q tile + 128x64 Vt tile with its 4 waves
#define STAGE(j0v, Qd, Vd) do {                                               \
    _Pragma("unroll")                                                         \
    for (int e_ = 0; e_ < 4; ++e_) {                                          \
        int r_ = 16 * wg + 4 * e_ + (l >> 4);                                 \
        GLDS(qbase + (size_t)((j0v) + r_) * QKVN +                            \
                 (((l & 15) ^ (r_ & 7)) * 8),                                 \
             (Qd) + (16 * wg + 4 * e_) * 128);                                \
        int d_ = 32 * wg + 8 * e_ + (l >> 3);                                 \
        GLDS(vbase + (size_t)d_ * 1024 + (j0v) + (((l & 7) ^ (d_ & 7)) * 8),  \
             (Vd) + (32 * wg + 8 * e_) * 64);                                 \
    }                                                                         \
} while (0)

#pragma unroll 1
    for (int ph = 0; ph < 2; ++ph) {
        const int it = ph ? x : (15 - x);
        const int nt = it + 1;
        const int half = (nt + 1) >> 1;           // group A count (>= B)
        const int cnt = grp ? (nt - half) : half; // my group's tile count
        const int jbase = grp ? half * 64 : 0;
        const int iw = it * 64 + wg * 16;

        // K fragments: row i = iw + ll, d = 8lg + e + 32c
        f16x8 kf[4];
        {
            const u16* kp = qkv + (size_t)(b * TT + iw + ll) * QKVN + KOFF + hk * 128 + lg * 8;
#pragma unroll
            for (int c = 0; c < 4; ++c) kf[c] = *(const f16x8*)(kp + 32 * c);
        }

        f32x4 o[8] = {};
        float mrun[4] = {-1e30f, -1e30f, -1e30f, -1e30f};
        float lrun[4] = {0.f, 0.f, 0.f, 0.f};

        if (cnt > 0) STAGE(jbase, QT[0], VT[0]);
        __syncthreads();

#pragma unroll 1
        for (int r = 0; r < half; ++r) {          // half >= cnt for both groups
            u16* Qc = QT[r & 1];
            u16* Vc = VT[r & 1];
            if (r + 1 < cnt) STAGE(jbase + (r + 1) * 64, QT[(r + 1) & 1], VT[(r + 1) & 1]);

            if (r < cnt) {
                const int jt = (grp ? half : 0) + r;
                f32x4 s[4] = {};
                __builtin_amdgcn_s_setprio(1);
#pragma unroll
                for (int kc = 0; kc < 4; ++kc)
#pragma unroll
                    for (int n = 0; n < 4; ++n) {
                        f16x8 qf = *(const f16x8*)&Qc[(16 * n + ll) * 128 + (((lg + 4 * kc) ^ (ll & 7)) * 8)];
                        s[n] = __builtin_amdgcn_mfma_f32_16x16x32_f16(kf[kc], qf, s[n], 0, 0, 0);
                    }
                __builtin_amdgcn_s_setprio(0);

                if (jt == it) {                   // diagonal tile: causal mask
#pragma unroll
                    for (int n = 0; n < 4; ++n)
#pragma unroll
                        for (int rr = 0; rr < 4; ++rr)
                            s[n][rr] = (16 * n + ll <= 16 * wg + 4 * lg + rr) ? s[n][rr] : -1e30f;
                }

                float tml[4];
                bool need = false;
#pragma unroll
                for (int rr = 0; rr < 4; ++rr) {
                    float tm = fmaxf(fmaxf(s[0][rr], s[1][rr]), fmaxf(s[2][rr], s[3][rr]));
                    tml[rr] = tm;
                    need |= (tm > mrun[rr] + 8.0f);
                }
                if (__any(need)) {
#pragma unroll
                    for (int rr = 0; rr < 4; ++rr) {
                        float tm = tml[rr];
                        tm = fmaxf(tm, __shfl_xor(tm, 1, 16));
                        tm = fmaxf(tm, __shfl_xor(tm, 2, 16));
                        tm = fmaxf(tm, __shfl_xor(tm, 4, 16));
                        tm = fmaxf(tm, __shfl_xor(tm, 8, 16));
                        float mnew = fmaxf(mrun[rr], tm);
                        float al = __expf(mrun[rr] - mnew);
                        lrun[rr] *= al;
                        mrun[rr] = mnew;
#pragma unroll
                        for (int n = 0; n < 8; ++n) o[n][rr] *= al;
                    }
                }
                float p[4][4];
#pragma unroll
                for (int rr = 0; rr < 4; ++rr) {
                    float ps = 0.f;
#pragma unroll
                    for (int n = 0; n < 4; ++n) { p[n][rr] = __expf(s[n][rr] - mrun[rr]); ps += p[n][rr]; }
                    lrun[rr] += ps;               // per-lane partial
                }

                // P: D-layout -> per-wave LDS (stride 72) -> A-layout frags
                u16* pw = Ps + w * (16 * 72);
#pragma unroll
                for (int n = 0; n < 4; ++n)
#pragma unroll
                    for (int rr = 0; rr < 4; ++rr)
                        pw[(4 * lg + rr) * 72 + ll + 16 * n] = f2h(p[n][rr]);
                f16x8 pa0 = *(const f16x8*)&pw[ll * 72 + 8 * lg];
                f16x8 pa1 = *(const f16x8*)&pw[ll * 72 + 8 * lg + 32];

                __builtin_amdgcn_s_setprio(1);
#pragma unroll
                for (int n = 0; n < 8; ++n) {
                    f16x8 vf0 = *(const f16x8*)&Vc[(16 * n + ll) * 64 + ((lg ^ (ll & 7)) * 8)];
                    o[n] = __builtin_amdgcn_mfma_f32_16x16x32_f16(pa0, vf0, o[n], 0, 0, 0);
                    f16x8 vf1 = *(const f16x8*)&Vc[(16 * n + ll) * 64 + (((lg + 4) ^ (ll & 7)) * 8)];
                    o[n] = __builtin_amdgcn_mfma_f32_16x16x32_f16(pa1, vf1, o[n], 0, 0, 0);
                }
                __builtin_amdgcn_s_setprio(0);
            }

            __syncthreads();   // next tile staged + LDS reuse
        }

        // ---- merge: group B dumps (o, m, l); group A combines + writes ----
        // staging buffers are dead past this point (all compute done)
        if (grp == 1) {
            const int base = (wg * 64 + l) * 40;
#pragma unroll
            for (int n = 0; n < 8; ++n)
#pragma unroll
                for (int rr = 0; rr < 4; ++rr)
                    sc[base + n * 4 + rr] = o[n][rr];
#pragma unroll
            for (int rr = 0; rr < 4; ++rr) {
                sc[base + 32 + rr] = mrun[rr];
                sc[base + 36 + rr] = lrun[rr];
            }
        }
        __syncthreads();
        if (grp == 0) {
            const int base = (wg * 64 + l) * 40;
            u16* dst = attnb + (size_t)(b * TT + iw + 4 * lg) * CC + h * 128 + ll;
#pragma unroll
            for (int rr = 0; rr < 4; ++rr) {
                float mB = sc[base + 32 + rr];
                float lB = sc[base + 36 + rr];
                float m  = fmaxf(mrun[rr], mB);
                float aA = __expf(mrun[rr] - m);
                float aB = __expf(mB - m);
                float L = lrun[rr] * aA + lB * aB;
                L += __shfl_xor(L, 1, 16);
                L += __shfl_xor(L, 2, 16);
                L += __shfl_xor(L, 4, 16);
                L += __shfl_xor(L, 8, 16);
                float inv = 1.0f / L;
#pragma unroll
                for (int n = 0; n < 8; ++n) {
                    float oo = o[n][rr] * aA + sc[base + n * 4 + rr] * aB;
                    dst[(size_t)rr * CC + 16 * n] = f2h(oo * inv);
                }
            }
        }
        __syncthreads();   // protect SM reuse by next phase's staging
    }
#undef STAGE
}

// ---------------------------------------------------------------------------
extern "C" void kernel_launch(void* const* d_in, const int* in_sizes, int n_in,
                              void* d_out, int out_size, void* d_ws, size_t ws_size,
                              hipStream_t stream) {
    const float* x      = (const float*)d_in[0];
    const float* angles = (const float*)d_in[1];
    const float* wq     = (const float*)d_in[2];
    const float* wk     = (const float*)d_in[3];
    const float* wv     = (const float*)d_in[4];
    const float* wo     = (const float*)d_in[5];
    float* out = (float*)d_out;

    char* ws = (char*)d_ws;
    u16*    Wt1   = (u16*)ws;                         // [0, 12.58M)  qkv weights^T
    u16*    Wt2   = (u16*)(ws + 12582912);            // [12.58M, 20.97M)  wo^T
    float2* cs    = (float2*)(ws + 20971520);         // [20.97M, 21.5M)   sincos table
    u16*    xb    = (u16*)(ws + 21495808);            // [21.5M, 29.9M)
    u16*    qkvb  = (u16*)(ws + 29884416);            // [29.9M, 42.5M)  q,k regions
    u16*    vtg   = (u16*)(ws + 42467328);            // [42.5M, 44.6M)  V^T
    u16*    attnb = (u16*)(ws + 44564480);            // [44.6M, 53.0M)

    // 1. all conversions + sincos table (one launch)
    prep<<<14592, 256, 0, stream>>>(x, wq, wk, wv, wo, angles, xb, Wt1, Wt2, cs);
    // 2. QKV projection (512 blocks, XCD-swizzled), fused RoPE + V^T epilogue
    gemm_qkv<<<512, 256, 0, stream>>>(xb, Wt1, qkvb, vtg, cs);
    // 3. attention (j-split flash-decoding, 9-round balanced critical path)
    attn_mfma<<<dim3(8, BB * NH), 512, 0, stream>>>(qkvb, vtg, attnb);
    // 4. output projection (128x64 tiles, 2 blocks/CU, XCD-swizzled), fp32 out
    gemm_out<<<512, 256, 0, stream>>>(attnb, Wt2, out);
}

// Round 19
// 112.496 us; speedup vs baseline: 1.0464x; 1.0464x over previous
//
#include <hip/hip_runtime.h>
#include <hip/hip_bf16.h>
#include <math.h>

#define BB 2
#define TT 1024
#define CC 2048
#define NH 16
#define NKV 4
#define HD 128
#define MROWS 2048
#define QKVN 3072              // 2048 q + 512 k + 512 v
#define KOFF 2048
#define VOFF 2560

typedef unsigned short u16;
typedef unsigned int   u32;
typedef _Float16 f16;
typedef _Float16 f16x8 __attribute__((ext_vector_type(8)));
typedef short    s16x8 __attribute__((ext_vector_type(8)));
typedef float    f32x4 __attribute__((ext_vector_type(4)));

__device__ __forceinline__ u16 f2h(float f) {
    union { f16 h; u16 u; } x; x.h = (f16)f; return x.u;
}
__device__ __forceinline__ float h2f(u16 u) {
    union { u16 u; f16 h; } x; x.u = u; return (float)x.h;
}

#define GLDS(gp, lp) __builtin_amdgcn_global_load_lds( \
    (const __attribute__((address_space(1))) u32*)(gp), \
    (__attribute__((address_space(3))) u32*)(lp), 16, 0, 0)

// ---------------------------------------------------------------------------
// wT_tile: one 32x32 transpose-convert tile
// ---------------------------------------------------------------------------
__device__ __forceinline__ void wT_tile(const float* __restrict__ src,
                                        u16* __restrict__ Wt, int Nsrc,
                                        int row_off, int idx, int t,
                                        float tile[32][33]) {
    const int k0 = (idx & 63) * 32;
    const int n0 = (idx >> 6) * 32;
    const int r = t >> 3, c4 = (t & 7) * 4;
    float4 v = *(const float4*)&src[(size_t)(k0 + r) * Nsrc + n0 + c4];
    tile[r][c4 + 0] = v.x; tile[r][c4 + 1] = v.y;
    tile[r][c4 + 2] = v.z; tile[r][c4 + 3] = v.w;
    __syncthreads();
    ushort4 o;
    o.x = f2h(tile[c4 + 0][r]); o.y = f2h(tile[c4 + 1][r]);
    o.z = f2h(tile[c4 + 2][r]); o.w = f2h(tile[c4 + 3][r]);
    *(ushort4*)&Wt[(size_t)(row_off + n0 + r) * 2048 + k0 + c4] = o;
}

// ---------------------------------------------------------------------------
// prep: one launch for all conversions (x->f16, 4x W^T, sincos table).
// ---------------------------------------------------------------------------
__global__ __launch_bounds__(256) void prep(const float* __restrict__ x,
                                            const float* __restrict__ wq,
                                            const float* __restrict__ wk,
                                            const float* __restrict__ wv,
                                            const float* __restrict__ wo,
                                            const float* __restrict__ angles,
                                            u16* __restrict__ xb,
                                            u16* __restrict__ Wt1,
                                            u16* __restrict__ Wt2,
                                            float2* __restrict__ cs) {
    __shared__ float tile[32][33];
    const int bid = blockIdx.x, t = threadIdx.x;
    if (bid < 4096) {                 // x -> fp16, 4 elems/thread
        int i = bid * 256 + t;
        float4 v = ((const float4*)x)[i];
        ushort4 o;
        o.x = f2h(v.x); o.y = f2h(v.y); o.z = f2h(v.z); o.w = f2h(v.w);
        ((ushort4*)xb)[i] = o;
    } else if (bid < 8192) {
        wT_tile(wq, Wt1, 2048, 0,    bid - 4096, t, tile);
    } else if (bid < 9216) {
        wT_tile(wk, Wt1, 512,  2048, bid - 8192, t, tile);
    } else if (bid < 10240) {
        wT_tile(wv, Wt1, 512,  2560, bid - 9216, t, tile);
    } else if (bid < 14336) {
        wT_tile(wo, Wt2, 2048, 0,    bid - 10240, t, tile);
    } else {
        int i = (bid - 14336) * 256 + t;   // < 65536
        float a = angles[i];
        cs[i] = make_float2(cosf(a), sinf(a));
    }
}

// ---------------------------------------------------------------------------
// gemm_qkv: [2048x2048] @ [3072x2048]^T, 128x96 tiles -> 512 blocks
// (XCD-swizzled), 4 waves (2x2, wave tile 64x48), 16x16x32 MFMAs, BK=64 dbuf.
// Fused epilogue: RoPE (q,k) + transposed V^T writes.
// ---------------------------------------------------------------------------
__global__ __launch_bounds__(256) void gemm_qkv(const u16* __restrict__ A,
                                                const u16* __restrict__ Bt,
                                                u16* __restrict__ qkv,
                                                u16* __restrict__ vtg,
                                                const float2* __restrict__ cs) {
    __shared__ __align__(16) u16 As0[128 * 64];
    __shared__ __align__(16) u16 As1[128 * 64];
    __shared__ __align__(16) u16 Bs0[96 * 64];
    __shared__ __align__(16) u16 Bs1[96 * 64];
    const int t = threadIdx.x, l = t & 63, w = t >> 6;
    const int bid = blockIdx.x;                 // 512
    const int xcd = bid & 7, idx = bid >> 3;    // 64 blocks per XCD
    const int bx = xcd * 4 + (idx & 3);         // col-tile 0..31
    const int by = idx >> 2;                    // row-tile 0..15
    const int row0 = by * 128;
    const int col0 = bx * 96;
    const int wr = w >> 1, wc = w & 1;
    const int lg = l >> 4, ll = l & 15;
    const int K = 2048;

    f32x4 acc[4][3] = {};

#define QSTAGE(AS, BS, k0v) do {                                              \
    _Pragma("unroll")                                                         \
    for (int e_ = 0; e_ < 4; ++e_) {                                          \
        int r_ = 32 * w + 8 * e_ + (l >> 3);                                  \
        int cg_ = (l & 7) ^ (r_ & 7);                                         \
        GLDS(A + (size_t)(row0 + r_) * K + (k0v) + cg_ * 8,                   \
             (AS) + (32 * w + 8 * e_) * 64);                                  \
    }                                                                         \
    _Pragma("unroll")                                                         \
    for (int e_ = 0; e_ < 3; ++e_) {                                          \
        int r_ = 24 * w + 8 * e_ + (l >> 3);                                  \
        int cg_ = (l & 7) ^ (r_ & 7);                                         \
        GLDS(Bt + (size_t)(col0 + r_) * K + (k0v) + cg_ * 8,                  \
             (BS) + (24 * w + 8 * e_) * 64);                                  \
    }                                                                         \
} while (0)

#define QCOMP(AS, BS) do {                                                    \
    _Pragma("unroll")                                                         \
    for (int kc_ = 0; kc_ < 2; ++kc_) {                                       \
        f16x8 af_[4], bf_[3];                                                 \
        _Pragma("unroll")                                                     \
        for (int m_ = 0; m_ < 4; ++m_) {                                      \
            int row_ = wr * 64 + 16 * m_ + ll;                                \
            af_[m_] = *(const f16x8*)&(AS)[row_ * 64 +                        \
                        (((lg + 4 * kc_) ^ (ll & 7)) * 8)];                   \
        }                                                                     \
        _Pragma("unroll")                                                     \
        for (int n_ = 0; n_ < 3; ++n_) {                                      \
            int col_ = wc * 48 + 16 * n_ + ll;                                \
            bf_[n_] = *(const f16x8*)&(BS)[col_ * 64 +                        \
                        (((lg + 4 * kc_) ^ (ll & 7)) * 8)];                   \
        }                                                                     \
        _Pragma("unroll")                                                     \
        for (int m_ = 0; m_ < 4; ++m_)                                        \
            _Pragma("unroll")                                                 \
            for (int n_ = 0; n_ < 3; ++n_)                                    \
                acc[m_][n_] = __builtin_amdgcn_mfma_f32_16x16x32_f16(         \
                    af_[m_], bf_[n_], acc[m_][n_], 0, 0, 0);                  \
    }                                                                         \
} while (0)

    QSTAGE(As0, Bs0, 0);
    __syncthreads();
#pragma unroll 1
    for (int i = 0; i < 32; i += 2) {
        QSTAGE(As1, Bs1, (i + 1) * 64);
        QCOMP(As0, Bs0);
        __syncthreads();
        if (i + 2 < 32) QSTAGE(As0, Bs0, (i + 2) * 64);
        QCOMP(As1, Bs1);
        __syncthreads();
    }
#undef QSTAGE
#undef QCOMP

    // fused epilogue
    const int orow = row0 + wr * 64 + lg * 4;
    const int ocol = col0 + wc * 48 + ll;
#pragma unroll
    for (int n = 0; n < 3; ++n) {
        const int col = ocol + 16 * n;
        if (col < VOFF) {
            // RoPE: pair (even,odd) cols live in adjacent lanes
            const int p = (col & 127) >> 1;
            const bool odd = ll & 1;
#pragma unroll
            for (int m = 0; m < 4; ++m) {
#pragma unroll
                for (int r = 0; r < 4; ++r) {
                    float v = acc[m][n][r];
                    float pr = __shfl_xor(v, 1);
                    int row = orow + 16 * m + r;
                    float2 a = cs[(row & (TT - 1)) * 64 + p];
                    float res = odd ? (a.y * pr + a.x * v) : (a.x * v - a.y * pr);
                    qkv[(size_t)row * QKVN + col] = f2h(res);
                }
            }
        } else {
            // V: write transposed, 4 consecutive j per ushort4
            int d = col - VOFF;
            const int hk = d >> 7; d &= 127;
            const int bb = orow >> 10;        // block rows never straddle b
            const int base_j = orow & (TT - 1);
#pragma unroll
            for (int m = 0; m < 4; ++m) {
                ushort4 pk;
                pk.x = f2h(acc[m][n][0]); pk.y = f2h(acc[m][n][1]);
                pk.z = f2h(acc[m][n][2]); pk.w = f2h(acc[m][n][3]);
                *(ushort4*)&vtg[((size_t)(bb * NKV + hk) * 128 + d) * 1024 + base_j + 16 * m] = pk;
            }
        }
    }
}

// ---------------------------------------------------------------------------
// gemm_out v5: [2048x2048] @ [2048x2048]^T, 128x64 tiles -> 512 blocks =
// 2 blocks/CU, 4 waves (2x2, wave tile 64x32), 16x16x32 MFMAs, BK=64 dbuf,
// LDS 48 KB, fp32 direct out, XCD-swizzled.
// ---------------------------------------------------------------------------
__global__ __launch_bounds__(256) void gemm_out(const u16* __restrict__ A,
                                                const u16* __restrict__ Bt,
                                                float* __restrict__ Cf) {
    __shared__ __align__(16) u16 As0[128 * 64];
    __shared__ __align__(16) u16 As1[128 * 64];
    __shared__ __align__(16) u16 Bs0[64 * 64];
    __shared__ __align__(16) u16 Bs1[64 * 64];
    const int t = threadIdx.x, l = t & 63, w = t >> 6;
    const int bid = blockIdx.x;                 // 512
    const int xcd = bid & 7, idx = bid >> 3;    // 64 blocks per XCD
    const int bx = xcd * 4 + (idx & 3);         // col-tile 0..31
    const int by = idx >> 2;                    // row-tile 0..15
    const int row0 = by * 128;
    const int col0 = bx * 64;
    const int wr = w >> 1, wc = w & 1;
    const int lg = l >> 4, ll = l & 15;
    const int K = 2048;

    f32x4 acc[4][2] = {};

#define GSTAGE(AS, BS, k0v) do {                                              \
    _Pragma("unroll")                                                         \
    for (int e_ = 0; e_ < 4; ++e_) {                                          \
        int r_ = 32 * w + 8 * e_ + (l >> 3);                                  \
        int cg_ = (l & 7) ^ (r_ & 7);                                         \
        GLDS(A + (size_t)(row0 + r_) * K + (k0v) + cg_ * 8,                   \
             (AS) + (32 * w + 8 * e_) * 64);                                  \
    }                                                                         \
    _Pragma("unroll")                                                         \
    for (int e_ = 0; e_ < 2; ++e_) {                                          \
        int r_ = 16 * w + 8 * e_ + (l >> 3);                                  \
        int cg_ = (l & 7) ^ (r_ & 7);                                         \
        GLDS(Bt + (size_t)(col0 + r_) * K + (k0v) + cg_ * 8,                  \
             (BS) + (16 * w + 8 * e_) * 64);                                  \
    }                                                                         \
} while (0)

#define GCOMP(AS, BS) do {                                                    \
    _Pragma("unroll")                                                         \
    for (int kc_ = 0; kc_ < 2; ++kc_) {                                       \
        f16x8 af_[4], bf_[2];                                                 \
        _Pragma("unroll")                                                     \
        for (int m_ = 0; m_ < 4; ++m_) {                                      \
            int row_ = wr * 64 + 16 * m_ + ll;                                \
            af_[m_] = *(const f16x8*)&(AS)[row_ * 64 +                        \
                        (((lg + 4 * kc_) ^ (ll & 7)) * 8)];                   \
        }                                                                     \
        _Pragma("unroll")                                                     \
        for (int n_ = 0; n_ < 2; ++n_) {                                      \
            int col_ = wc * 32 + 16 * n_ + ll;                                \
            bf_[n_] = *(const f16x8*)&(BS)[col_ * 64 +                        \
                        (((lg + 4 * kc_) ^ (ll & 7)) * 8)];                   \
        }                                                                     \
        _Pragma("unroll")                                                     \
        for (int m_ = 0; m_ < 4; ++m_)                                        \
            _Pragma("unroll")                                                 \
            for (int n_ = 0; n_ < 2; ++n_)                                    \
                acc[m_][n_] = __builtin_amdgcn_mfma_f32_16x16x32_f16(         \
                    af_[m_], bf_[n_], acc[m_][n_], 0, 0, 0);                  \
    }                                                                         \
} while (0)

    GSTAGE(As0, Bs0, 0);
    __syncthreads();
#pragma unroll 1
    for (int i = 0; i < 32; i += 2) {
        GSTAGE(As1, Bs1, (i + 1) * 64);
        GCOMP(As0, Bs0);
        __syncthreads();
        if (i + 2 < 32) GSTAGE(As0, Bs0, (i + 2) * 64);
        GCOMP(As1, Bs1);
        __syncthreads();
    }
#undef GSTAGE
#undef GCOMP

    const int orow = row0 + wr * 64 + lg * 4;
    const int ocol = col0 + wc * 32 + ll;
#pragma unroll
    for (int m = 0; m < 4; ++m)
#pragma unroll
        for (int nn = 0; nn < 2; ++nn)
#pragma unroll
            for (int r = 0; r < 4; ++r)
                Cf[(size_t)(orow + 16 * m + r) * CC + ocol + 16 * nn] =
                    acc[m][nn][r];
}

// ---------------------------------------------------------------------------
// MFMA flash attention v4 + setprio (T5): 8 waves/block, paired i-tiles
// {x, 15-x} share one staged Q/Vt double-buffer; defer-max rescale.
// (round-17 version — the j-split v5 restructure regressed +4.7 µs)
// ---------------------------------------------------------------------------
__global__ __launch_bounds__(512, 2) void attn_mfma(const u16* __restrict__ qkv,
                                                    const u16* __restrict__ vtg,
                                                    u16* __restrict__ attnb) {
    __shared__ __align__(16) u16 Qs0[64 * 128];
    __shared__ __align__(16) u16 Qs1[64 * 128];
    __shared__ __align__(16) u16 Vt0[128 * 64];
    __shared__ __align__(16) u16 Vt1[128 * 64];
    __shared__ __align__(16) u16 Ps[8 * 16 * 72];

    const int t = threadIdx.x, l = t & 63, w = t >> 6;   // w in 0..7
    const int bh = blockIdx.y;
    const int b = bh >> 4, h = bh & 15, hk = h & 3;
    const int lg = l >> 4, ll = l & 15;
    const int wl = w & 3;                 // wave-in-half
    const int x = blockIdx.x;             // 0..7
    const int myIt = (w < 4) ? x : (15 - x);
    const int iw = myIt * 64 + wl * 16;

    const u16* qbase = qkv + (size_t)(b * TT) * QKVN + h * 128;
    const u16* vbase = vtg + (size_t)((b * NKV + hk) * 128) * 1024;

#define STAGE(j0v, Qd, Vd) do {                                               \
    _Pragma("unroll")                                                         \
    for (int e_ = 0; e_ < 2; ++e_) {                                          \
        int r_ = 4 * (2 * w + e_) + (l >> 4);                                 \
        GLDS(qbase + (size_t)((j0v) + r_) * QKVN +                            \
                 (((l & 15) ^ (r_ & 7)) * 8),                                 \
             (Qd) + 4 * (2 * w + e_) * 128);                                  \
        int d_ = 8 * (2 * w + e_) + (l >> 3);                                 \
        GLDS(vbase + (size_t)d_ * 1024 + (j0v) + (((l & 7) ^ (d_ & 7)) * 8),  \
             (Vd) + 8 * (2 * w + e_) * 64);                                   \
    }                                                                         \
} while (0)

    f16x8 kf[4];
    {
        const u16* kp = qkv + (size_t)(b * TT + iw + ll) * QKVN + KOFF + hk * 128 + lg * 8;
#pragma unroll
        for (int c = 0; c < 4; ++c) kf[c] = *(const f16x8*)(kp + 32 * c);
    }

    f32x4 o[8] = {};
    float mrun[4] = {-1e30f, -1e30f, -1e30f, -1e30f};
    float lrun[4] = {0.f, 0.f, 0.f, 0.f};

    const int nt = 16 - x;    // j-tiles for the big half
    STAGE(0, Qs0, Vt0);
    __syncthreads();

#pragma unroll 1
    for (int jt = 0; jt < nt; ++jt) {
        u16* Qc = (jt & 1) ? Qs1 : Qs0;
        u16* Vc = (jt & 1) ? Vt1 : Vt0;
        if (jt + 1 < nt) {
            u16* Qn = (jt & 1) ? Qs0 : Qs1;
            u16* Vn = (jt & 1) ? Vt0 : Vt1;
            STAGE((jt + 1) * 64, Qn, Vn);
        }

        if (jt <= myIt) {                 // wave-uniform
            f32x4 s[4] = {};
            __builtin_amdgcn_s_setprio(1);
#pragma unroll
            for (int kc = 0; kc < 4; ++kc)
#pragma unroll
                for (int n = 0; n < 4; ++n) {
                    f16x8 qf = *(const f16x8*)&Qc[(16 * n + ll) * 128 + (((lg + 4 * kc) ^ (ll & 7)) * 8)];
                    s[n] = __builtin_amdgcn_mfma_f32_16x16x32_f16(kf[kc], qf, s[n], 0, 0, 0);
                }
            __builtin_amdgcn_s_setprio(0);

            if (jt == myIt) {             // diagonal: causal mask
#pragma unroll
                for (int n = 0; n < 4; ++n)
#pragma unroll
                    for (int r = 0; r < 4; ++r)
                        s[n][r] = (16 * n + ll <= 16 * wl + 4 * lg + r) ? s[n][r] : -1e30f;
            }

            float tml[4];
            bool need = false;
#pragma unroll
            for (int r = 0; r < 4; ++r) {
                float tm = fmaxf(fmaxf(s[0][r], s[1][r]), fmaxf(s[2][r], s[3][r]));
                tml[r] = tm;
                need |= (tm > mrun[r] + 8.0f);
            }
            if (__any(need)) {
#pragma unroll
                for (int r = 0; r < 4; ++r) {
                    float tm = tml[r];
                    tm = fmaxf(tm, __shfl_xor(tm, 1, 16));
                    tm = fmaxf(tm, __shfl_xor(tm, 2, 16));
                    tm = fmaxf(tm, __shfl_xor(tm, 4, 16));
                    tm = fmaxf(tm, __shfl_xor(tm, 8, 16));
                    float mnew = fmaxf(mrun[r], tm);
                    float al = __expf(mrun[r] - mnew);
                    lrun[r] *= al;
                    mrun[r] = mnew;
#pragma unroll
                    for (int n = 0; n < 8; ++n) o[n][r] *= al;
                }
            }
            float p[4][4];
#pragma unroll
            for (int r = 0; r < 4; ++r) {
                float ps = 0.f;
#pragma unroll
                for (int n = 0; n < 4; ++n) { p[n][r] = __expf(s[n][r] - mrun[r]); ps += p[n][r]; }
                lrun[r] += ps;            // per-lane partial; reduced in epilogue
            }

            // P: D-layout -> per-wave LDS (stride 72) -> A-layout fragments
            u16* pw = Ps + w * (16 * 72);
#pragma unroll
            for (int n = 0; n < 4; ++n)
#pragma unroll
                for (int r = 0; r < 4; ++r)
                    pw[(4 * lg + r) * 72 + ll + 16 * n] = f2h(p[n][r]);
            f16x8 pa0 = *(const f16x8*)&pw[ll * 72 + 8 * lg];
            f16x8 pa1 = *(const f16x8*)&pw[ll * 72 + 8 * lg + 32];

            __builtin_amdgcn_s_setprio(1);
#pragma unroll
            for (int n = 0; n < 8; ++n) {
                f16x8 vf0 = *(const f16x8*)&Vc[(16 * n + ll) * 64 + ((lg ^ (ll & 7)) * 8)];
                o[n] = __builtin_amdgcn_mfma_f32_16x16x32_f16(pa0, vf0, o[n], 0, 0, 0);
                f16x8 vf1 = *(const f16x8*)&Vc[(16 * n + ll) * 64 + (((lg + 4) ^ (ll & 7)) * 8)];
                o[n] = __builtin_amdgcn_mfma_f32_16x16x32_f16(pa1, vf1, o[n], 0, 0, 0);
            }
            __builtin_amdgcn_s_setprio(0);
        }

        __syncthreads();   // drains vmcnt (next tile staged) + LDS reuse
    }

    // epilogue
    u16* dst = attnb + (size_t)(b * TT + iw + 4 * lg) * CC + h * 128 + ll;
#pragma unroll
    for (int r = 0; r < 4; ++r) {
        float L = lrun[r];
        L += __shfl_xor(L, 1, 16);
        L += __shfl_xor(L, 2, 16);
        L += __shfl_xor(L, 4, 16);
        L += __shfl_xor(L, 8, 16);
        float inv = 1.0f / L;
#pragma unroll
        for (int n = 0; n < 8; ++n)
            dst[(size_t)r * CC + 16 * n] = f2h(o[n][r] * inv);
    }
#undef STAGE
}

// ---------------------------------------------------------------------------
extern "C" void kernel_launch(void* const* d_in, const int* in_sizes, int n_in,
                              void* d_out, int out_size, void* d_ws, size_t ws_size,
                              hipStream_t stream) {
    const float* x      = (const float*)d_in[0];
    const float* angles = (const float*)d_in[1];
    const float* wq     = (const float*)d_in[2];
    const float* wk     = (const float*)d_in[3];
    const float* wv     = (const float*)d_in[4];
    const float* wo     = (const float*)d_in[5];
    float* out = (float*)d_out;

    char* ws = (char*)d_ws;
    u16*    Wt1   = (u16*)ws;                         // [0, 12.58M)  qkv weights^T
    u16*    Wt2   = (u16*)(ws + 12582912);            // [12.58M, 20.97M)  wo^T
    float2* cs    = (float2*)(ws + 20971520);         // [20.97M, 21.5M)   sincos table
    u16*    xb    = (u16*)(ws + 21495808);            // [21.5M, 29.9M)
    u16*    qkvb  = (u16*)(ws + 29884416);            // [29.9M, 42.5M)  q,k regions
    u16*    vtg   = (u16*)(ws + 42467328);            // [42.5M, 44.6M)  V^T
    u16*    attnb = (u16*)(ws + 44564480);            // [44.6M, 53.0M)

    // 1. all conversions + sincos table (one launch)
    prep<<<14592, 256, 0, stream>>>(x, wq, wk, wv, wo, angles, xb, Wt1, Wt2, cs);
    // 2. QKV projection (512 blocks, XCD-swizzled), fused RoPE + V^T epilogue
    gemm_qkv<<<512, 256, 0, stream>>>(xb, Wt1, qkvb, vtg, cs);
    // 3. attention (8-wave shared-staging + setprio)
    attn_mfma<<<dim3(8, BB * NH), 512, 0, stream>>>(qkvb, vtg, attnb);
    // 4. output projection (128x64 tiles, 2 blocks/CU, XCD-swizzled), fp32 out
    gemm_out<<<512, 256, 0, stream>>>(attnb, Wt2, out);
}